// Round 1
// baseline (995.480 us; speedup 1.0000x reference)
//
#include <hip/hip_runtime.h>
#include <hip/hip_bf16.h>
#include <math.h>

#define DIMD 256
#define DIMC 64
#define WT_STRIDE 264  // 256 + 8 pad (bf16) -> 528 B row = 132 dwords, 132%32==4 -> even bank spread

typedef __attribute__((ext_vector_type(8))) __bf16 bf16x8;
typedef __attribute__((ext_vector_type(4))) float f32x4;

__global__ __launch_bounds__(256, 2) void tree_node_kernel(
    const float* __restrict__ x,
    const float* __restrict__ w_router,
    const float* __restrict__ b_router,
    const float* __restrict__ w_left,
    const float* __restrict__ b_left,
    const float* __restrict__ w_right,
    const float* __restrict__ b_right,
    float* __restrict__ out,
    int tiles_per_block)
{
    // W transposed: wt[col][k], cols 0..63 = w_left, 64..127 = w_right, bf16
    __shared__ __bf16 wt[128 * WT_STRIDE];   // 67,584 B
    __shared__ float  wr_s[DIMD];            // router weights fp32

    const int tid  = threadIdx.x;
    const int lane = tid & 63;
    const int wave = tid >> 6;
    const int g    = lane >> 4;   // k-group 0..3
    const int m    = lane & 15;   // row (A) / col (B) within 16-tile

    // ---- stage weights to LDS (once per block) ----
    for (int idx = tid; idx < DIMD * DIMC; idx += 256) {
        int d = idx >> 6, c = idx & 63;      // w is [D][C] row-major
        wt[c * WT_STRIDE + d]        = (__bf16)w_left[idx];
        wt[(64 + c) * WT_STRIDE + d] = (__bf16)w_right[idx];
    }
    if (tid < DIMD) wr_s[tid] = w_router[tid];
    __syncthreads();

    const float brout = b_router[0];

    // per-lane biases for the 4 output col-tiles
    float biasL[4], biasR[4];
#pragma unroll
    for (int t = 0; t < 4; ++t) {
        biasL[t] = b_left[t * 16 + m];
        biasR[t] = b_right[t * 16 + m];
    }

    const int tile0 = blockIdx.x * tiles_per_block;

    for (int it = 0; it < tiles_per_block; ++it) {
        const int tile = tile0 + it;
        const int row_wave = tile * 64 + wave * 16;      // this wave's 16-row tile base
        const float* xrow = x + (size_t)(row_wave + m) * DIMD;

        // ---- load this lane's 64 x values (fp32), 16 dwordx4 in flight ----
        f32x4 ax[8][2];
#pragma unroll
        for (int s = 0; s < 8; ++s) {
            const int ks = s * 32 + g * 8;
            ax[s][0] = *(const f32x4*)(xrow + ks);
            ax[s][1] = *(const f32x4*)(xrow + ks + 4);
        }

        // ---- router logit in fp64 (sign must match reference) ----
        double rsum = 0.0;
#pragma unroll
        for (int s = 0; s < 8; ++s) {
            const int ks = s * 32 + g * 8;
#pragma unroll
            for (int j = 0; j < 4; ++j) {
                rsum += (double)ax[s][0][j] * (double)wr_s[ks + j];
                rsum += (double)ax[s][1][j] * (double)wr_s[ks + 4 + j];
            }
        }
        rsum += __shfl_xor(rsum, 16);
        rsum += __shfl_xor(rsum, 32);
        const float logitf = (float)(rsum + (double)brout);
        const float p = 1.0f / (1.0f + expf(-logitf));
        const unsigned long long bal = __ballot(p > 0.5f);  // bits 0..15 <-> rows 0..15

        // ---- MFMA: 8 K-steps x 8 N-tiles (0-3 left cols, 4-7 right cols) ----
        f32x4 acc[8];
#pragma unroll
        for (int t = 0; t < 8; ++t) acc[t] = (f32x4){0.f, 0.f, 0.f, 0.f};

#pragma unroll
        for (int s = 0; s < 8; ++s) {
            bf16x8 a;
#pragma unroll
            for (int j = 0; j < 4; ++j) {
                a[j]     = (__bf16)ax[s][0][j];
                a[j + 4] = (__bf16)ax[s][1][j];
            }
            const int kb = s * 32 + g * 8;
#pragma unroll
            for (int t = 0; t < 8; ++t) {
                const bf16x8 b = *(const bf16x8*)&wt[(t * 16 + m) * WT_STRIDE + kb];
                acc[t] = __builtin_amdgcn_mfma_f32_16x16x32_bf16(a, b, acc[t], 0, 0, 0);
            }
        }

        // ---- epilogue: select child per row, add bias, store ----
        float* orow = out + (size_t)row_wave * DIMC;
#pragma unroll
        for (int t = 0; t < 4; ++t) {
#pragma unroll
            for (int r = 0; r < 4; ++r) {
                const int row = g * 4 + r;                 // C/D layout: row=(lane>>4)*4+reg
                const bool left = (bal >> row) & 1ULL;
                const float v = left ? (acc[t][r] + biasL[t])
                                     : (acc[t + 4][r] + biasR[t]);
                orow[(size_t)row * DIMC + t * 16 + m] = v;
            }
        }
    }
}

extern "C" void kernel_launch(void* const* d_in, const int* in_sizes, int n_in,
                              void* d_out, int out_size, void* d_ws, size_t ws_size,
                              hipStream_t stream) {
    const float* x        = (const float*)d_in[0];
    const float* w_router = (const float*)d_in[1];
    const float* b_router = (const float*)d_in[2];
    const float* w_left   = (const float*)d_in[3];
    const float* b_left   = (const float*)d_in[4];
    const float* w_right  = (const float*)d_in[5];
    const float* b_right  = (const float*)d_in[6];
    float* out = (float*)d_out;

    const int n_tok = in_sizes[0] / DIMD;        // 1,048,576
    const int tiles = n_tok / 64;                // 16,384 row-tiles
    const int grid  = 512;                       // 2 blocks/CU (LDS-limited)
    const int tpb   = tiles / grid;              // 32 tiles per block

    tree_node_kernel<<<grid, 256, 0, stream>>>(
        x, w_router, b_router, w_left, b_left, w_right, b_right, out, tpb);
}

// Round 2
// 351.344 us; speedup vs baseline: 2.8333x; 2.8333x over previous
//
#include <hip/hip_runtime.h>
#include <hip/hip_bf16.h>
#include <math.h>

#define DIMD 256
#define DIMC 64
#define RPT  16   // rows per block-iteration

typedef __attribute__((ext_vector_type(8))) __bf16 bf16x8;
typedef __attribute__((ext_vector_type(4))) float f32x4;

__global__ __launch_bounds__(256, 4) void tree_node_kernel(
    const float* __restrict__ x,
    const float* __restrict__ w_router,
    const float* __restrict__ b_router,
    const float* __restrict__ w_left,
    const float* __restrict__ b_left,
    const float* __restrict__ w_right,
    const float* __restrict__ b_right,
    float* __restrict__ out,
    int iters)
{
    // LDS: 2x16KB x-tiles (XOR-swizzled image) + 4KB out bounce + router w + masks
    __shared__ float xbuf[2][RPT * DIMD];
    __shared__ float out_tile[RPT * DIMC];
    __shared__ float wr_s[DIMD];
    __shared__ int   mask_lds[RPT];

    const int tid  = threadIdx.x;
    const int lane = tid & 63;
    const int wave = tid >> 6;
    const int g    = lane >> 4;   // k-group 0..3
    const int m    = lane & 15;   // row (A) / col (B) within 16-tile

    // ---- stage next x tile: one global_load_lds dwordx4 instr == one 1KB row ----
    // LDS image is XOR-swizzled per 16B piece: piece' = piece ^ (row&7).
    // global_load_lds writes linearly (base + lane*16), so we pre-swizzle the
    // per-lane GLOBAL source offset instead (rule #21).
    auto stage = [&](int buf, size_t row0) {
#pragma unroll
        for (int i = 0; i < 4; ++i) {
            const int rl = i * 4 + wave;                      // local row 0..15
            const float* gsrc = x + (row0 + (size_t)rl) * DIMD
                                  + (((lane * 4) ^ ((rl & 7) << 2)));
            __builtin_amdgcn_global_load_lds(
                (const __attribute__((address_space(1))) void*)gsrc,
                (__attribute__((address_space(3))) void*)(&xbuf[buf][rl * DIMD]),
                16, 0, 0);
        }
    };

    const size_t block_row0 = (size_t)blockIdx.x * (size_t)iters * RPT;

    // prologue: stage tile 0, router weights to LDS
    stage(0, block_row0);
    wr_s[tid] = w_router[tid];

    // ---- B fragments in registers: wave w owns output cols [w*16, w*16+16) ----
    const int col = wave * 16 + m;
    bf16x8 bL[8], bR[8];
#pragma unroll
    for (int s = 0; s < 8; ++s) {
#pragma unroll
        for (int j = 0; j < 8; ++j) {
            const int k = s * 32 + g * 8 + j;
            bL[s][j] = (__bf16)w_left[k * DIMC + col];
            bR[s][j] = (__bf16)w_right[k * DIMC + col];
        }
    }
    const float biasL = b_left[col];
    const float biasR = b_right[col];
    const float brout = b_router[0];

    __syncthreads();   // tile 0 staged (implicit vmcnt(0)), wr_s ready

    int cur = 0;
    for (int it = 0; it < iters; ++it) {
        if (it + 1 < iters) stage(cur ^ 1, block_row0 + (size_t)(it + 1) * RPT);

        const float* xb = &xbuf[cur][0];

        // ---- router (fp64 accumulate; sign decides child) ----
        // lane handles row wave*4+g, k-chunk [m*16, m*16+16)
        const int rrow = wave * 4 + g;
        const int rxr  = rrow & 7;
        double racc = 0.0;
#pragma unroll
        for (int u = 0; u < 4; ++u) {
            const f32x4 xv = *(const f32x4*)&xb[rrow * DIMD + (((m * 4 + u) ^ rxr) << 2)];
            const f32x4 wv = *(const f32x4*)&wr_s[m * 16 + u * 4];
#pragma unroll
            for (int j = 0; j < 4; ++j)
                racc += (double)xv[j] * (double)wv[j];
        }
        racc += __shfl_xor(racc, 1);
        racc += __shfl_xor(racc, 2);
        racc += __shfl_xor(racc, 4);
        racc += __shfl_xor(racc, 8);
        const float logitf = (float)(racc + (double)brout);
        const float p = 1.0f / (1.0f + expf(-logitf));
        if (m == 0) mask_lds[rrow] = (p > 0.5f) ? 1 : 0;

        // ---- MFMA: 8 K-steps, both children, cols owned by this wave ----
        f32x4 accL = {0.f, 0.f, 0.f, 0.f}, accR = {0.f, 0.f, 0.f, 0.f};
        const int axr = m & 7;
#pragma unroll
        for (int s = 0; s < 8; ++s) {
            const int q0 = s * 8 + g * 2;                    // 16B piece index
            const f32x4 lo = *(const f32x4*)&xb[m * DIMD + ((q0 ^ axr) << 2)];
            const f32x4 hi = *(const f32x4*)&xb[m * DIMD + (((q0 + 1) ^ axr) << 2)];
            bf16x8 a;
#pragma unroll
            for (int j = 0; j < 4; ++j) {
                a[j]     = (__bf16)lo[j];
                a[j + 4] = (__bf16)hi[j];
            }
            accL = __builtin_amdgcn_mfma_f32_16x16x32_bf16(a, bL[s], accL, 0, 0, 0);
            accR = __builtin_amdgcn_mfma_f32_16x16x32_bf16(a, bR[s], accR, 0, 0, 0);
        }

        __syncthreads();   // masks ready; prev store's out_tile reads done

        // ---- epilogue: select child, write 16x64 out tile to LDS ----
#pragma unroll
        for (int r = 0; r < 4; ++r) {
            const int row = g * 4 + r;                        // C/D: row=(lane>>4)*4+reg
            const float v = mask_lds[row] ? (accL[r] + biasL) : (accR[r] + biasR);
            out_tile[row * DIMC + wave * 16 + m] = v;
        }

        __syncthreads();   // out_tile ready

        // ---- linear store: 256 threads x 16B = 4KB contiguous ----
        const f32x4 ov = *(const f32x4*)&out_tile[tid * 4];
        *(f32x4*)(out + (block_row0 + (size_t)it * RPT) * DIMC + tid * 4) = ov;

        __syncthreads();   // drains vmcnt(0): staged tile complete before swap
        cur ^= 1;
    }
}

extern "C" void kernel_launch(void* const* d_in, const int* in_sizes, int n_in,
                              void* d_out, int out_size, void* d_ws, size_t ws_size,
                              hipStream_t stream) {
    const float* x        = (const float*)d_in[0];
    const float* w_router = (const float*)d_in[1];
    const float* b_router = (const float*)d_in[2];
    const float* w_left   = (const float*)d_in[3];
    const float* b_left   = (const float*)d_in[4];
    const float* w_right  = (const float*)d_in[5];
    const float* b_right  = (const float*)d_in[6];
    float* out = (float*)d_out;

    const int n_tok = in_sizes[0] / DIMD;   // 1,048,576
    const int grid  = 1024;                 // 4 blocks/CU x 256 CU
    const int iters = n_tok / (grid * RPT); // 64

    tree_node_kernel<<<grid, 256, 0, stream>>>(
        x, w_router, b_router, w_left, b_left, w_right, b_right, out, iters);
}

// Round 3
// 319.827 us; speedup vs baseline: 3.1126x; 1.0985x over previous
//
#include <hip/hip_runtime.h>
#include <hip/hip_bf16.h>

#define DIMD 256
#define DIMC 64
#define RPT  16   // rows per block-iteration
#define OTS  68   // out_tile row stride (floats); 68%32==4 -> 2-way max on writes

typedef __attribute__((ext_vector_type(8))) __bf16 bf16x8;
typedef __attribute__((ext_vector_type(4))) float f32x4;
typedef __attribute__((ext_vector_type(4))) int i32x4;

__global__ __launch_bounds__(256, 4) void tree_node_kernel(
    const float* __restrict__ x,
    const float* __restrict__ w_router,
    const float* __restrict__ b_router,
    const float* __restrict__ w_left,
    const float* __restrict__ b_left,
    const float* __restrict__ w_right,
    const float* __restrict__ b_right,
    float* __restrict__ out,
    int iters)
{
    __shared__ float xbuf[2][RPT * DIMD];                    // 32 KB, XOR-swizzled image
    __shared__ float out_tile[RPT * OTS];                    // 4.25 KB bounce
    __shared__ float wr_s[DIMD];
    __shared__ int   mask_lds[RPT] __attribute__((aligned(16)));

    const int tid  = threadIdx.x;
    const int lane = tid & 63;
    const int wave = tid >> 6;
    const int g    = lane >> 4;   // k-group 0..3
    const int m    = lane & 15;   // row (A) / col (B) within 16-tile

    // one global_load_lds dwordx4 == one contiguous 1KB row; LDS image swizzled
    // per 16B piece (piece' = piece ^ (row&7)) via pre-swizzled GLOBAL source
    // (rule #21: linear LDS dest, swizzle source + reads with same involution).
    auto stage = [&](int buf, size_t row0) {
#pragma unroll
        for (int i = 0; i < 4; ++i) {
            const int rl = i * 4 + wave;                      // local row 0..15
            const float* gsrc = x + (row0 + (size_t)rl) * DIMD
                                  + ((lane * 4) ^ ((rl & 7) << 2));
            __builtin_amdgcn_global_load_lds(
                (const __attribute__((address_space(1))) void*)gsrc,
                (__attribute__((address_space(3))) void*)(&xbuf[buf][rl * DIMD]),
                16, 0, 0);
        }
    };

    const size_t block_row0 = (size_t)blockIdx.x * (size_t)iters * RPT;

    // ---- weights -> registers FIRST (consumed before staging; keeps the
    //      prologue vmcnt accounting simple: stage loads are the newest) ----
    const int col = wave * 16 + m;                           // this wave's output col
    bf16x8 bL[8], bR[8];
#pragma unroll
    for (int s = 0; s < 8; ++s)
#pragma unroll
        for (int j = 0; j < 8; ++j) {
            const int k = s * 32 + g * 8 + j;
            bL[s][j] = (__bf16)w_left[k * DIMC + col];
            bR[s][j] = (__bf16)w_right[k * DIMC + col];
        }
    const float biasL = b_left[col];
    const float biasR = b_right[col];
    const float brout = b_router[0];
    wr_s[tid] = w_router[tid];

    stage(0, block_row0);
    asm volatile("s_waitcnt vmcnt(0)" ::: "memory");
    asm volatile("s_waitcnt lgkmcnt(0)" ::: "memory");
    __builtin_amdgcn_s_barrier();

    for (int it = 0; it < iters; ++it) {
        const int cur = it & 1;
        // prefetch tile it+1 into the other buffer; NOT waited until barrier C
        if (it + 1 < iters) stage(cur ^ 1, block_row0 + (size_t)(it + 1) * RPT);

        const float* xb = &xbuf[cur][0];

        // ---- router: fp64 accumulate, sign decides child (p>0.5 <=> logit>0) ----
        const int rrow = wave * 4 + g;                       // lane's router row
        const int rxr  = rrow & 7;
        double racc = 0.0;
#pragma unroll
        for (int u = 0; u < 4; ++u) {
            const f32x4 xv = *(const f32x4*)&xb[rrow * DIMD + (((m * 4 + u) ^ rxr) << 2)];
            const f32x4 wv = *(const f32x4*)&wr_s[m * 16 + u * 4];
#pragma unroll
            for (int j = 0; j < 4; ++j)
                racc += (double)xv[j] * (double)wv[j];
        }
        racc += __shfl_xor(racc, 1);
        racc += __shfl_xor(racc, 2);
        racc += __shfl_xor(racc, 4);
        racc += __shfl_xor(racc, 8);
        if (m == 0)
            mask_lds[rrow] = ((float)(racc + (double)brout) > 0.0f) ? 1 : 0;

        // ---- MFMA: 8 K-steps, both children, this wave's 16 cols ----
        f32x4 accL = {0.f,0.f,0.f,0.f}, accR = {0.f,0.f,0.f,0.f};
        const int axr = m & 7;
#pragma unroll
        for (int s = 0; s < 8; ++s) {
            const int q0 = s * 8 + g * 2;                    // 16B piece index
            const f32x4 lo = *(const f32x4*)&xb[m * DIMD + ((q0 ^ axr) << 2)];
            const f32x4 hi = *(const f32x4*)&xb[m * DIMD + (((q0 + 1) ^ axr) << 2)];
            bf16x8 a;
#pragma unroll
            for (int j = 0; j < 4; ++j) {
                a[j]     = (__bf16)lo[j];
                a[j + 4] = (__bf16)hi[j];
            }
            accL = __builtin_amdgcn_mfma_f32_16x16x32_bf16(a, bL[s], accL, 0, 0, 0);
            accR = __builtin_amdgcn_mfma_f32_16x16x32_bf16(a, bR[s], accR, 0, 0, 0);
        }

        // ---- barrier A: mask visible; NO vmcnt drain (prefetch stays in flight) ----
        asm volatile("s_waitcnt lgkmcnt(0)" ::: "memory");
        __builtin_amdgcn_s_barrier();

        // ---- epilogue: select child per row, bounce 16x64 tile through LDS ----
        const i32x4 mk = *(const i32x4*)&mask_lds[g * 4];
#pragma unroll
        for (int r = 0; r < 4; ++r) {
            const int row = g * 4 + r;                       // C/D: row=(lane>>4)*4+reg
            const float v = mk[r] ? (accL[r] + biasL) : (accR[r] + biasR);
            out_tile[row * OTS + col] = v;
        }

        // ---- barrier B: out_tile visible; still no vmcnt drain ----
        asm volatile("s_waitcnt lgkmcnt(0)" ::: "memory");
        __builtin_amdgcn_s_barrier();

        // ---- linear store: 256 threads x 16B = 4KB contiguous ----
        const f32x4 ov = *(const f32x4*)&out_tile[(tid >> 4) * OTS + (tid & 15) * 4];
        *(f32x4*)(out + (block_row0 + (size_t)it * RPT) * DIMC + (size_t)tid * 4) = ov;

        // ---- barrier C: counted wait — retires next-tile loads (+prev store),
        //      leaves this iter's store in flight ----
        asm volatile("s_waitcnt vmcnt(1)" ::: "memory");
        __builtin_amdgcn_s_barrier();
    }
}

extern "C" void kernel_launch(void* const* d_in, const int* in_sizes, int n_in,
                              void* d_out, int out_size, void* d_ws, size_t ws_size,
                              hipStream_t stream) {
    const float* x        = (const float*)d_in[0];
    const float* w_router = (const float*)d_in[1];
    const float* b_router = (const float*)d_in[2];
    const float* w_left   = (const float*)d_in[3];
    const float* b_left   = (const float*)d_in[4];
    const float* w_right  = (const float*)d_in[5];
    const float* b_right  = (const float*)d_in[6];
    float* out = (float*)d_out;

    const int n_tok = in_sizes[0] / DIMD;   // 1,048,576
    const int grid  = 1024;                 // 4 blocks/CU x 256 CU
    const int iters = n_tok / (grid * RPT); // 64

    tree_node_kernel<<<grid, 256, 0, stream>>>(
        x, w_router, b_router, w_left, b_left, w_right, b_right, out, iters);
}

// Round 4
// 315.446 us; speedup vs baseline: 3.1558x; 1.0139x over previous
//
#include <hip/hip_runtime.h>
#include <hip/hip_bf16.h>

#define DIMD 256
#define DIMC 64
#define RPT  16   // rows per block-iteration
#define OTS  68   // out-bounce row stride (floats)
#define NBUF 3    // x-tile ring depth (prefetch distance 2)

typedef __attribute__((ext_vector_type(8))) __bf16 bf16x8;
typedef __attribute__((ext_vector_type(4))) float f32x4;

__global__ __launch_bounds__(256, 2) void tree_node_kernel(
    const float* __restrict__ x,
    const float* __restrict__ w_router,
    const float* __restrict__ b_router,
    const float* __restrict__ w_left,
    const float* __restrict__ b_left,
    const float* __restrict__ w_right,
    const float* __restrict__ b_right,
    float* __restrict__ out,
    int iters)
{
    __shared__ float xbuf[NBUF][RPT * DIMD];   // 48 KB, XOR-swizzled image
    __shared__ float obuf[2][RPT * OTS];       // 8.5 KB double-buffered bounce
    __shared__ float wr_s[DIMD];               // 1 KB router weights

    const int tid  = threadIdx.x;
    const int lane = tid & 63;
    const int wave = tid >> 6;
    const int g    = lane >> 4;   // k-group 0..3
    const int m    = lane & 15;   // row (A) / col (B) within 16-tile

    // one global_load_lds dwordx4 == one contiguous 1KB row; LDS image swizzled
    // per 16B piece (piece' = piece ^ (row&7)) via pre-swizzled GLOBAL source
    // (rule #21: linear LDS dest; same involution on source and reads).
    auto stage = [&](int slot, size_t row0) {
#pragma unroll
        for (int i = 0; i < 4; ++i) {
            const int rl = i * 4 + wave;                      // local row 0..15
            const float* gsrc = x + (row0 + (size_t)rl) * DIMD
                                  + ((lane * 4) ^ ((rl & 7) << 2));
            __builtin_amdgcn_global_load_lds(
                (const __attribute__((address_space(1))) void*)gsrc,
                (__attribute__((address_space(3))) void*)(&xbuf[slot][rl * DIMD]),
                16, 0, 0);
        }
    };

    // ---- prologue: weights -> registers, router weights -> LDS ----
    const int col = wave * 16 + m;                           // this wave's output col
    bf16x8 bL[8], bR[8];
#pragma unroll
    for (int s = 0; s < 8; ++s)
#pragma unroll
        for (int j = 0; j < 8; ++j) {
            const int k = s * 32 + g * 8 + j;
            bL[s][j] = (__bf16)w_left[k * DIMC + col];
            bR[s][j] = (__bf16)w_right[k * DIMC + col];
        }
    const float biasL = b_left[col];
    const float biasR = b_right[col];
    const float brout = b_router[0];
    wr_s[tid] = w_router[tid];

    const size_t block_row0 = (size_t)blockIdx.x * (size_t)iters * RPT;

    stage(0, block_row0);
    stage(1, block_row0 + RPT);
    asm volatile("s_waitcnt lgkmcnt(0)" ::: "memory");
    asm volatile("s_waitcnt vmcnt(4)" ::: "memory");   // tile0 done; tile1 in flight
    __builtin_amdgcn_s_barrier();

    for (int it = 0; it < iters; ++it) {
        // ---- 1) store PREVIOUS tile (written to bounce before last barrier):
        //         256 threads x 16B = 4KB fully contiguous ----
        if (it > 0) {
            const f32x4 ov = *(const f32x4*)
                &obuf[(it - 1) & 1][(tid >> 4) * OTS + (tid & 15) * 4];
            *(f32x4*)(out + (block_row0 + (size_t)(it - 1) * RPT) * DIMC
                          + (size_t)tid * 4) = ov;
        }

        // ---- 2) prefetch tile it+2 (distance 2; slot of tile it-1, free) ----
        if (it + 2 < iters) stage((it + 2) % NBUF, block_row0 + (size_t)(it + 2) * RPT);

        // ---- 3) compute tile it: MFMA + folded fp64 router ----
        const float* xb = &xbuf[it % NBUF][0];
        f32x4 accL = {0.f,0.f,0.f,0.f}, accR = {0.f,0.f,0.f,0.f};
        double racc = 0.0;
        const int axr = m & 7;
#pragma unroll
        for (int s = 0; s < 8; ++s) {
            const int q0 = s * 8 + g * 2;                    // logical 16B piece
            const f32x4 lo  = *(const f32x4*)&xb[m * DIMD + ((q0 ^ axr) << 2)];
            const f32x4 hi  = *(const f32x4*)&xb[m * DIMD + (((q0 + 1) ^ axr) << 2)];
            const f32x4 wlo = *(const f32x4*)&wr_s[s * 32 + g * 8];      // broadcast
            const f32x4 whi = *(const f32x4*)&wr_s[s * 32 + g * 8 + 4];  // broadcast
            bf16x8 a;
#pragma unroll
            for (int j = 0; j < 4; ++j) {
                a[j]     = (__bf16)lo[j];
                a[j + 4] = (__bf16)hi[j];
                racc += (double)lo[j] * (double)wlo[j];
                racc += (double)hi[j] * (double)whi[j];
            }
            accL = __builtin_amdgcn_mfma_f32_16x16x32_bf16(a, bL[s], accL, 0, 0, 0);
            accR = __builtin_amdgcn_mfma_f32_16x16x32_bf16(a, bR[s], accR, 0, 0, 0);
        }
        // lane holds row-m partial over k in {s*32+g*8+0..7}; sum over g:
        racc += __shfl_xor(racc, 16);
        racc += __shfl_xor(racc, 32);
        const bool leftbit = ((float)(racc + (double)brout) > 0.0f);
        const unsigned long long bal = __ballot(leftbit);    // bit l&15 <-> row l&15

        // ---- 4) epilogue: select child per row, write bounce (pre-barrier) ----
#pragma unroll
        for (int r = 0; r < 4; ++r) {
            const int row = g * 4 + r;                       // C/D: row=(lane>>4)*4+reg
            const float v = ((bal >> row) & 1ULL) ? (accL[r] + biasL)
                                                  : (accR[r] + biasR);
            obuf[it & 1][row * OTS + col] = v;
        }

        // ---- 5) single barrier: publishes bounce + tile it+1 readiness.
        //         Counted vmcnt keeps stage(it+2) (and this store) in flight ----
        asm volatile("s_waitcnt lgkmcnt(0)" ::: "memory");
        if (it + 2 < iters) {
            if (it > 0) asm volatile("s_waitcnt vmcnt(5)" ::: "memory");
            else        asm volatile("s_waitcnt vmcnt(4)" ::: "memory");
        } else {
            asm volatile("s_waitcnt vmcnt(1)" ::: "memory");
        }
        __builtin_amdgcn_s_barrier();
    }

    // ---- drain: store last tile ----
    {
        const int it = iters - 1;
        const f32x4 ov = *(const f32x4*)
            &obuf[it & 1][(tid >> 4) * OTS + (tid & 15) * 4];
        *(f32x4*)(out + (block_row0 + (size_t)it * RPT) * DIMC
                      + (size_t)tid * 4) = ov;
    }
}

extern "C" void kernel_launch(void* const* d_in, const int* in_sizes, int n_in,
                              void* d_out, int out_size, void* d_ws, size_t ws_size,
                              hipStream_t stream) {
    const float* x        = (const float*)d_in[0];
    const float* w_router = (const float*)d_in[1];
    const float* b_router = (const float*)d_in[2];
    const float* w_left   = (const float*)d_in[3];
    const float* b_left   = (const float*)d_in[4];
    const float* w_right  = (const float*)d_in[5];
    const float* b_right  = (const float*)d_in[6];
    float* out = (float*)d_out;

    const int n_tok = in_sizes[0] / DIMD;   // 1,048,576
    const int grid  = 512;                  // 2 blocks/CU x 256 CU (LDS ~58 KB)
    const int iters = n_tok / (grid * RPT); // 128

    tree_node_kernel<<<grid, 256, 0, stream>>>(
        x, w_router, b_router, w_left, b_left, w_right, b_right, out, iters);
}

// Round 5
// 305.187 us; speedup vs baseline: 3.2619x; 1.0336x over previous
//
#include <hip/hip_runtime.h>
#include <hip/hip_bf16.h>

#define DIMD 256
#define DIMC 64
#define RPT  16   // rows per block-iteration
#define OTS  68   // out-bounce row stride (floats)

typedef __attribute__((ext_vector_type(8))) __bf16 bf16x8;
typedef __attribute__((ext_vector_type(4))) __bf16 bf16x4;
typedef __attribute__((ext_vector_type(4))) float f32x4;
typedef __attribute__((ext_vector_type(4))) int i32x4;

__global__ __launch_bounds__(256, 4) void tree_node_kernel(
    const float* __restrict__ x,
    const float* __restrict__ w_router,
    const float* __restrict__ b_router,
    const float* __restrict__ w_left,
    const float* __restrict__ b_left,
    const float* __restrict__ w_right,
    const float* __restrict__ b_right,
    float* __restrict__ out,
    int iters)
{
    // x tiles in bf16 (converted at stage time), XOR-swizzled per 16B piece
    __shared__ __bf16 xb16[2][RPT * DIMD];                  // 2 x 8 KB
    __shared__ float  obuf[2][RPT * OTS];                   // 8.5 KB bounce
    __shared__ float  wr_s[DIMD];                           // 1 KB router w
    __shared__ int    mask_lds[2][RPT] __attribute__((aligned(16)));

    const int tid  = threadIdx.x;
    const int lane = tid & 63;
    const int wave = tid >> 6;
    const int g    = lane >> 4;   // k-group 0..3 (MFMA)
    const int m    = lane & 15;   // row (A) / col (B) within 16-tile
    const int srow = tid >> 4;    // staging row 0..15 (block-wide role)
    const int sm   = tid & 15;    // staging chunk 0..15

    // ---- prologue: B weights -> registers (wave w owns cols [16w,16w+16)) ----
    const int col = wave * 16 + m;
    bf16x8 bL[8], bR[8];
#pragma unroll
    for (int s = 0; s < 8; ++s)
#pragma unroll
        for (int j = 0; j < 8; ++j) {
            const int k = s * 32 + g * 8 + j;
            bL[s][j] = (__bf16)w_left[k * DIMC + col];
            bR[s][j] = (__bf16)w_right[k * DIMC + col];
        }
    const float biasL = b_left[col];
    const float biasR = b_right[col];
    const float brout = b_router[0];
    wr_s[tid] = w_router[tid];

    const size_t block_row0 = (size_t)blockIdx.x * (size_t)iters * RPT;

    __syncthreads();   // wr_s ready (read at lane-crossing indices below)

    // ---- stage tile 0: f32 global->reg, fp64 router partial, cvt->bf16->LDS.
    //      lane covers row srow, k in {4*sm+64j .. +4}; swizzle piece^=(row&7).
    {
        const float* xr = x + (block_row0 + (size_t)srow) * DIMD + sm * 4;
        f32x4 sx[4];
#pragma unroll
        for (int j = 0; j < 4; ++j) sx[j] = *(const f32x4*)(xr + j * 64);
        double racc = 0.0;
        const int rx = srow & 7;
#pragma unroll
        for (int j = 0; j < 4; ++j) {
            const f32x4 wv = *(const f32x4*)&wr_s[sm * 4 + j * 64];
            bf16x4 v;
#pragma unroll
            for (int e = 0; e < 4; ++e) {
                racc += (double)sx[j][e] * (double)wv[e];
                v[e] = (__bf16)sx[j][e];
            }
            const int p = (sm >> 1) + 8 * j;               // logical 16B piece
            *(bf16x4*)&xb16[0][srow * DIMD + (((p ^ rx) << 3) | ((sm & 1) << 2))] = v;
        }
        racc += __shfl_xor(racc, 1);
        racc += __shfl_xor(racc, 2);
        racc += __shfl_xor(racc, 4);
        racc += __shfl_xor(racc, 8);
        if (sm == 0)
            mask_lds[0][srow] = ((float)(racc + (double)brout) > 0.0f) ? 1 : 0;
    }
    __syncthreads();

    for (int it = 0; it < iters; ++it) {
        // ---- 1) T14 issue: next tile's global loads -> registers (early) ----
        f32x4 sx[4];
        const bool do_stage = (it + 1 < iters);
        if (do_stage) {
            const float* xr = x + (block_row0 + (size_t)(it + 1) * RPT + srow) * DIMD
                                + sm * 4;
#pragma unroll
            for (int j = 0; j < 4; ++j) sx[j] = *(const f32x4*)(xr + j * 64);
        }

        // ---- 2) store PREVIOUS tile: 256 threads x 16B = 4KB contiguous ----
        if (it > 0) {
            const f32x4 ov = *(const f32x4*)
                &obuf[(it - 1) & 1][(tid >> 4) * OTS + (tid & 15) * 4];
            *(f32x4*)(out + (block_row0 + (size_t)(it - 1) * RPT) * DIMC
                          + (size_t)tid * 4) = ov;
        }

        // ---- 3) compute tile it: 8 K-steps, both children (A direct from LDS bf16) ----
        const __bf16* xb = &xb16[it & 1][0];
        f32x4 accL = {0.f,0.f,0.f,0.f}, accR = {0.f,0.f,0.f,0.f};
        const int axr = m & 7;
#pragma unroll
        for (int s = 0; s < 8; ++s) {
            const int p = s * 4 + g;
            const bf16x8 a = *(const bf16x8*)&xb[m * DIMD + ((p ^ axr) << 3)];
            accL = __builtin_amdgcn_mfma_f32_16x16x32_bf16(a, bL[s], accL, 0, 0, 0);
            accR = __builtin_amdgcn_mfma_f32_16x16x32_bf16(a, bR[s], accR, 0, 0, 0);
        }

        // ---- 4) epilogue: select child per row (mask staged last iter) ----
        const i32x4 mk = *(const i32x4*)&mask_lds[it & 1][g * 4];
#pragma unroll
        for (int r = 0; r < 4; ++r) {
            const float v = mk[r] ? (accL[r] + biasL) : (accR[r] + biasR);
            obuf[it & 1][(g * 4 + r) * OTS + col] = v;   // C/D: row=(lane>>4)*4+reg
        }

        // ---- 5) T14 consume: router fp64 + cvt + swizzled LDS write (late;
        //         compiler's auto vmcnt wait for sx lands HERE) ----
        if (do_stage) {
            const int slot = (it + 1) & 1;
            double racc = 0.0;
            const int rx = srow & 7;
#pragma unroll
            for (int j = 0; j < 4; ++j) {
                const f32x4 wv = *(const f32x4*)&wr_s[sm * 4 + j * 64];
                bf16x4 v;
#pragma unroll
                for (int e = 0; e < 4; ++e) {
                    racc += (double)sx[j][e] * (double)wv[e];
                    v[e] = (__bf16)sx[j][e];
                }
                const int p = (sm >> 1) + 8 * j;
                *(bf16x4*)&xb16[slot][srow * DIMD + (((p ^ rx) << 3) | ((sm & 1) << 2))] = v;
            }
            racc += __shfl_xor(racc, 1);
            racc += __shfl_xor(racc, 2);
            racc += __shfl_xor(racc, 4);
            racc += __shfl_xor(racc, 8);
            if (sm == 0)
                mask_lds[slot][srow] = ((float)(racc + (double)brout) > 0.0f) ? 1 : 0;
        }

        // ---- 6) single barrier (loads already consumed; only an old store
        //         is in the vm queue, so the implicit vmcnt(0) drain is cheap) ----
        __syncthreads();
    }

    // ---- drain: store last tile ----
    {
        const int it = iters - 1;
        const f32x4 ov = *(const f32x4*)
            &obuf[it & 1][(tid >> 4) * OTS + (tid & 15) * 4];
        *(f32x4*)(out + (block_row0 + (size_t)it * RPT) * DIMC
                      + (size_t)tid * 4) = ov;
    }
}

extern "C" void kernel_launch(void* const* d_in, const int* in_sizes, int n_in,
                              void* d_out, int out_size, void* d_ws, size_t ws_size,
                              hipStream_t stream) {
    const float* x        = (const float*)d_in[0];
    const float* w_router = (const float*)d_in[1];
    const float* b_router = (const float*)d_in[2];
    const float* w_left   = (const float*)d_in[3];
    const float* b_left   = (const float*)d_in[4];
    const float* w_right  = (const float*)d_in[5];
    const float* b_right  = (const float*)d_in[6];
    float* out = (float*)d_out;

    const int n_tok = in_sizes[0] / DIMD;   // 1,048,576
    const int grid  = 1024;                 // 4 blocks/CU x 256 CU (LDS ~26 KB)
    const int iters = n_tok / (grid * RPT); // 64

    tree_node_kernel<<<grid, 256, 0, stream>>>(
        x, w_router, b_router, w_left, b_left, w_right, b_right, out, iters);
}

// Round 6
// 304.083 us; speedup vs baseline: 3.2737x; 1.0036x over previous
//
#include <hip/hip_runtime.h>
#include <hip/hip_bf16.h>

#define DIMD 256
#define DIMC 64
#define RPT  16   // rows per block-iteration
#define OTS  68   // out-bounce row stride (floats)

typedef __attribute__((ext_vector_type(8))) __bf16 bf16x8;
typedef __attribute__((ext_vector_type(4))) __bf16 bf16x4;
typedef __attribute__((ext_vector_type(4))) float f32x4;
typedef __attribute__((ext_vector_type(4))) int i32x4;

__global__ __launch_bounds__(256, 4) void tree_node_kernel(
    const float* __restrict__ x,
    const float* __restrict__ w_router,
    const float* __restrict__ b_router,
    const float* __restrict__ w_left,
    const float* __restrict__ b_left,
    const float* __restrict__ w_right,
    const float* __restrict__ b_right,
    float* __restrict__ out,
    int iters)
{
    __shared__ __bf16 xb16[2][RPT * DIMD];                  // 2 x 8 KB, swizzled
    __shared__ float  obuf[2][RPT * OTS];                   // 8.5 KB bounce
    __shared__ float  wr_s[DIMD];                           // 1 KB router w
    __shared__ int    mask_lds[2][RPT] __attribute__((aligned(16)));

    const int tid  = threadIdx.x;
    const int lane = tid & 63;
    const int wave = tid >> 6;
    const int g    = lane >> 4;   // k-group 0..3 (MFMA)
    const int m    = lane & 15;   // row (A) / col (B) within 16-tile
    const int srow = tid >> 4;    // staging row 0..15
    const int sm   = tid & 15;    // staging chunk 0..15

    // ---- prologue: B weights -> registers (wave w owns cols [16w,16w+16)) ----
    const int col = wave * 16 + m;
    bf16x8 bL[8], bR[8];
#pragma unroll
    for (int s = 0; s < 8; ++s)
#pragma unroll
        for (int j = 0; j < 8; ++j) {
            const int k = s * 32 + g * 8 + j;
            bL[s][j] = (__bf16)w_left[k * DIMC + col];
            bR[s][j] = (__bf16)w_right[k * DIMC + col];
        }
    const float biasL = b_left[col];
    const float biasR = b_right[col];
    const float brout = b_router[0];
    wr_s[tid] = w_router[tid];

    const size_t block_row0 = (size_t)blockIdx.x * (size_t)iters * RPT;

    __syncthreads();   // wr_s ready

    f32x4 sx[4];       // staged f32 (one 16-float slice of one row)

    // issue: global loads for tile itile -> sx (4 x dwordx4, 256B-dense/16 lanes)
#define ISSUE(itile)                                                          \
    {                                                                         \
        const float* xr = x + (block_row0 + (size_t)(itile) * RPT + srow)     \
                            * DIMD + sm * 4;                                  \
        _Pragma("unroll")                                                     \
        for (int j = 0; j < 4; ++j) sx[j] = *(const f32x4*)(xr + j * 64);     \
    }

    // consume: fp64 router partial + cvt bf16 + swizzled LDS write + mask.
    // swizzle: 16B piece p -> p ^ (row&7); same involution on A-frag reads.
#define CONSUME(itile)                                                        \
    {                                                                         \
        const int slot = (itile) & 1;                                         \
        double racc = 0.0;                                                    \
        const int rx = srow & 7;                                              \
        _Pragma("unroll")                                                     \
        for (int j = 0; j < 4; ++j) {                                         \
            const f32x4 wv = *(const f32x4*)&wr_s[sm * 4 + j * 64];           \
            bf16x4 v;                                                         \
            _Pragma("unroll")                                                 \
            for (int e = 0; e < 4; ++e) {                                     \
                racc += (double)sx[j][e] * (double)wv[e];                     \
                v[e] = (__bf16)sx[j][e];                                      \
            }                                                                 \
            const int p = (sm >> 1) + 8 * j;                                  \
            *(bf16x4*)&xb16[slot][srow * DIMD +                               \
                (((p ^ rx) << 3) | ((sm & 1) << 2))] = v;                     \
        }                                                                     \
        racc += __shfl_xor(racc, 1);                                          \
        racc += __shfl_xor(racc, 2);                                          \
        racc += __shfl_xor(racc, 4);                                          \
        racc += __shfl_xor(racc, 8);                                          \
        if (sm == 0)                                                          \
            mask_lds[slot][srow] =                                            \
                ((float)(racc + (double)brout) > 0.0f) ? 1 : 0;               \
    }

    // ---- prologue staging: tile 0 staged, tile 1 loads left IN FLIGHT ----
    ISSUE(0);
    CONSUME(0);
    ISSUE(1);
    asm volatile("s_waitcnt lgkmcnt(0)" ::: "memory");
    __builtin_amdgcn_s_barrier();

    for (int it = 0; it < iters; ++it) {
        // ---- 1) store tile it-1 (obuf written before last barrier):
        //         256 threads x 16B = 4KB contiguous; ack never waited on ----
        if (it > 0) {
            const f32x4 ov = *(const f32x4*)
                &obuf[(it - 1) & 1][(tid >> 4) * OTS + (tid & 15) * 4];
            *(f32x4*)(out + (block_row0 + (size_t)(it - 1) * RPT) * DIMC
                          + (size_t)tid * 4) = ov;
        }

        // ---- 2) MFMA tile it: 8 K-steps, both children ----
        const __bf16* xb = &xb16[it & 1][0];
        f32x4 accL = {0.f,0.f,0.f,0.f}, accR = {0.f,0.f,0.f,0.f};
        const int axr = m & 7;
#pragma unroll
        for (int s = 0; s < 8; ++s) {
            const int p = s * 4 + g;
            const bf16x8 a = *(const bf16x8*)&xb[m * DIMD + ((p ^ axr) << 3)];
            accL = __builtin_amdgcn_mfma_f32_16x16x32_bf16(a, bL[s], accL, 0, 0, 0);
            accR = __builtin_amdgcn_mfma_f32_16x16x32_bf16(a, bR[s], accR, 0, 0, 0);
        }

        // ---- 3) consume tile it+1 (loads issued LAST iter; compiler waits
        //         vmcnt(1): the step-1 store is newer, stays in flight) ----
        if (it + 1 < iters) CONSUME(it + 1);

        // ---- 4) issue tile it+2 (sx regs just freed; these 4 loads stay
        //         in flight ACROSS the barrier -> no read-stream gap) ----
        if (it + 2 < iters) ISSUE(it + 2);

        // ---- 5) epilogue tile it: select child per row -> obuf[it&1] ----
        const i32x4 mk = *(const i32x4*)&mask_lds[it & 1][g * 4];
#pragma unroll
        for (int r = 0; r < 4; ++r) {
            const float v = mk[r] ? (accL[r] + biasL) : (accR[r] + biasR);
            obuf[it & 1][(g * 4 + r) * OTS + col] = v;   // C/D: row=(lane>>4)*4+reg
        }

        // ---- 6) barrier: lgkm-only (publishes xb16[it+1], mask, obuf).
        //         NO vmcnt drain: loads(it+2) + store(it-1) stay in flight ----
        asm volatile("s_waitcnt lgkmcnt(0)" ::: "memory");
        __builtin_amdgcn_s_barrier();
    }

    // ---- drain: store last tile ----
    {
        const int it = iters - 1;
        const f32x4 ov = *(const f32x4*)
            &obuf[it & 1][(tid >> 4) * OTS + (tid & 15) * 4];
        *(f32x4*)(out + (block_row0 + (size_t)it * RPT) * DIMC
                      + (size_t)tid * 4) = ov;
    }
#undef ISSUE
#undef CONSUME
}

extern "C" void kernel_launch(void* const* d_in, const int* in_sizes, int n_in,
                              void* d_out, int out_size, void* d_ws, size_t ws_size,
                              hipStream_t stream) {
    const float* x        = (const float*)d_in[0];
    const float* w_router = (const float*)d_in[1];
    const float* b_router = (const float*)d_in[2];
    const float* w_left   = (const float*)d_in[3];
    const float* b_left   = (const float*)d_in[4];
    const float* w_right  = (const float*)d_in[5];
    const float* b_right  = (const float*)d_in[6];
    float* out = (float*)d_out;

    const int n_tok = in_sizes[0] / DIMD;   // 1,048,576
    const int grid  = 1024;                 // 4 blocks/CU x 256 CU (LDS ~26 KB)
    const int iters = n_tok / (grid * RPT); // 64

    tree_node_kernel<<<grid, 256, 0, stream>>>(
        x, w_router, b_router, w_left, b_left, w_right, b_right, out, iters);
}

// Round 7
// 284.889 us; speedup vs baseline: 3.4943x; 1.0674x over previous
//
#include <hip/hip_runtime.h>
#include <hip/hip_bf16.h>

#define DIMD 256
#define DIMC 64
#define RPT  16   // rows per tile
#define OTS  68   // out-bounce row stride (floats)

typedef __attribute__((ext_vector_type(8))) __bf16 bf16x8;
typedef __attribute__((ext_vector_type(4))) __bf16 bf16x4;
typedef __attribute__((ext_vector_type(4))) float f32x4;
typedef __attribute__((ext_vector_type(4))) int i32x4;

__global__ __launch_bounds__(256, 4) void tree_node_kernel(
    const float* __restrict__ x,
    const float* __restrict__ w_router,
    const float* __restrict__ b_router,
    const float* __restrict__ w_left,
    const float* __restrict__ b_left,
    const float* __restrict__ w_right,
    const float* __restrict__ b_right,
    float* __restrict__ out,
    int iters)
{
    __shared__ __bf16 xb16[2][RPT * DIMD];                  // 2 x 8 KB, swizzled
    __shared__ float  obuf[2][RPT * OTS];                   // 8.5 KB bounce
    __shared__ float  wr_s[DIMD];                           // 1 KB router w
    __shared__ int    mask_lds[2][RPT] __attribute__((aligned(16)));

    const int tid  = threadIdx.x;
    const int lane = tid & 63;
    const int wave = tid >> 6;
    const int g    = lane >> 4;   // k-group 0..3 (MFMA)
    const int m    = lane & 15;   // row (A) / col (B) within 16-tile
    const int srow = tid >> 4;    // staging row 0..15
    const int sm   = tid & 15;    // staging chunk 0..15

    // ---- prologue: B weights -> registers (wave w owns cols [16w,16w+16)) ----
    const int col = wave * 16 + m;
    bf16x8 bL[8], bR[8];
#pragma unroll
    for (int s = 0; s < 8; ++s)
#pragma unroll
        for (int j = 0; j < 8; ++j) {
            const int k = s * 32 + g * 8 + j;
            bL[s][j] = (__bf16)w_left[k * DIMC + col];
            bR[s][j] = (__bf16)w_right[k * DIMC + col];
        }
    const float biasL = b_left[col];
    const float biasR = b_right[col];
    const float brout = b_router[0];
    wr_s[tid] = w_router[tid];

    // GRID-STRIDED tile mapping (dense moving front): iteration `it` of block b
    // processes rows [(it*grid + b)*16, +16). At any instant the whole chip
    // reads ONE contiguous ~16MB window instead of 1024 scattered streams.
    const size_t row_base    = (size_t)blockIdx.x * RPT;
    const size_t row_stride  = (size_t)gridDim.x * RPT;   // rows advanced per it
#define ROW0(itile) (row_base + (size_t)(itile) * row_stride)

    __syncthreads();   // wr_s ready

    f32x4 sx[4];       // staged f32 (one 16-float slice of one row)

#define ISSUE(itile)                                                          \
    {                                                                         \
        const float* xr = x + (ROW0(itile) + srow) * DIMD + sm * 4;           \
        _Pragma("unroll")                                                     \
        for (int j = 0; j < 4; ++j) sx[j] = *(const f32x4*)(xr + j * 64);     \
    }

    // consume: fp64 router partial + cvt bf16 + swizzled LDS write + mask.
    // swizzle: 16B piece p -> p ^ (row&7); same involution on A-frag reads.
#define CONSUME(itile)                                                        \
    {                                                                         \
        const int slot = (itile) & 1;                                         \
        double racc = 0.0;                                                    \
        const int rx = srow & 7;                                              \
        _Pragma("unroll")                                                     \
        for (int j = 0; j < 4; ++j) {                                         \
            const f32x4 wv = *(const f32x4*)&wr_s[sm * 4 + j * 64];           \
            bf16x4 v;                                                         \
            _Pragma("unroll")                                                 \
            for (int e = 0; e < 4; ++e) {                                     \
                racc += (double)sx[j][e] * (double)wv[e];                     \
                v[e] = (__bf16)sx[j][e];                                      \
            }                                                                 \
            const int p = (sm >> 1) + 8 * j;                                  \
            *(bf16x4*)&xb16[slot][srow * DIMD +                               \
                (((p ^ rx) << 3) | ((sm & 1) << 2))] = v;                     \
        }                                                                     \
        racc += __shfl_xor(racc, 1);                                          \
        racc += __shfl_xor(racc, 2);                                          \
        racc += __shfl_xor(racc, 4);                                          \
        racc += __shfl_xor(racc, 8);                                          \
        if (sm == 0)                                                          \
            mask_lds[slot][srow] =                                            \
                ((float)(racc + (double)brout) > 0.0f) ? 1 : 0;               \
    }

    // ---- prologue staging: tile 0 staged, tile 1 loads left IN FLIGHT ----
    ISSUE(0);
    CONSUME(0);
    ISSUE(1);
    asm volatile("s_waitcnt lgkmcnt(0)" ::: "memory");
    __builtin_amdgcn_s_barrier();

    for (int it = 0; it < iters; ++it) {
        // ---- 1) store tile it-1 (obuf written before last barrier):
        //         256 threads x 16B = 4KB contiguous; ack never waited on ----
        if (it > 0) {
            const f32x4 ov = *(const f32x4*)
                &obuf[(it - 1) & 1][(tid >> 4) * OTS + (tid & 15) * 4];
            *(f32x4*)(out + ROW0(it - 1) * DIMC + (size_t)tid * 4) = ov;
        }

        // ---- 2) MFMA tile it: 8 K-steps, both children ----
        const __bf16* xb = &xb16[it & 1][0];
        f32x4 accL = {0.f,0.f,0.f,0.f}, accR = {0.f,0.f,0.f,0.f};
        const int axr = m & 7;
#pragma unroll
        for (int s = 0; s < 8; ++s) {
            const int p = s * 4 + g;
            const bf16x8 a = *(const bf16x8*)&xb[m * DIMD + ((p ^ axr) << 3)];
            accL = __builtin_amdgcn_mfma_f32_16x16x32_bf16(a, bL[s], accL, 0, 0, 0);
            accR = __builtin_amdgcn_mfma_f32_16x16x32_bf16(a, bR[s], accR, 0, 0, 0);
        }

        // ---- 3) consume tile it+1 (loads issued LAST iter; compiler waits
        //         vmcnt(1): the step-1 store is newer, stays in flight) ----
        if (it + 1 < iters) CONSUME(it + 1);

        // ---- 4) issue tile it+2 (sx regs just freed; loads stay in flight
        //         ACROSS the barrier -> no read-stream gap) ----
        if (it + 2 < iters) ISSUE(it + 2);

        // ---- 5) epilogue tile it: select child per row -> obuf[it&1] ----
        const i32x4 mk = *(const i32x4*)&mask_lds[it & 1][g * 4];
#pragma unroll
        for (int r = 0; r < 4; ++r) {
            const float v = mk[r] ? (accL[r] + biasL) : (accR[r] + biasR);
            obuf[it & 1][(g * 4 + r) * OTS + col] = v;   // C/D: row=(lane>>4)*4+reg
        }

        // ---- 6) barrier: lgkm-only (publishes xb16[it+1], mask, obuf).
        //         NO vmcnt drain: loads(it+2) + store(it-1) stay in flight ----
        asm volatile("s_waitcnt lgkmcnt(0)" ::: "memory");
        __builtin_amdgcn_s_barrier();
    }

    // ---- drain: store last tile ----
    {
        const int it = iters - 1;
        const f32x4 ov = *(const f32x4*)
            &obuf[it & 1][(tid >> 4) * OTS + (tid & 15) * 4];
        *(f32x4*)(out + ROW0(it) * DIMC + (size_t)tid * 4) = ov;
    }
#undef ISSUE
#undef CONSUME
#undef ROW0
}

extern "C" void kernel_launch(void* const* d_in, const int* in_sizes, int n_in,
                              void* d_out, int out_size, void* d_ws, size_t ws_size,
                              hipStream_t stream) {
    const float* x        = (const float*)d_in[0];
    const float* w_router = (const float*)d_in[1];
    const float* b_router = (const float*)d_in[2];
    const float* w_left   = (const float*)d_in[3];
    const float* b_left   = (const float*)d_in[4];
    const float* w_right  = (const float*)d_in[5];
    const float* b_right  = (const float*)d_in[6];
    float* out = (float*)d_out;

    const int n_tok = in_sizes[0] / DIMD;   // 1,048,576
    const int grid  = 1024;                 // 4 blocks/CU x 256 CU (LDS ~26 KB)
    const int iters = n_tok / (grid * RPT); // 64

    tree_node_kernel<<<grid, 256, 0, stream>>>(
        x, w_router, b_router, w_left, b_left, w_right, b_right, out, iters);
}